// Round 1
// 610.880 us; speedup vs baseline: 1.3416x; 1.3416x over previous
//
#include <hip/hip_runtime.h>
#include <hip/hip_bf16.h>

#define D_IN 128
#define HDIM 128
#define D_E  32
#define NC   16
#define SCAN_CHUNK 2048

typedef __attribute__((ext_vector_type(8))) short short8;
typedef __attribute__((ext_vector_type(4))) float float4v;

__device__ inline short f2bs(float f) {
  __hip_bfloat16 h = (__hip_bfloat16)f;
  return *reinterpret_cast<short*>(&h);
}

__device__ inline float bs2f(short s) {
  unsigned int u = ((unsigned int)(unsigned short)s) << 16;
  float f;
  __builtin_memcpy(&f, &u, 4);
  return f;
}

// ---------------- prologue: degree, CSR ----------------

__global__ __launch_bounds__(256) void count_deg(const int* __restrict__ ei, int* __restrict__ deg, int E) {
  int e = blockIdx.x * 256 + threadIdx.x;
  if (e < E) atomicAdd(&deg[ei[E + e]], 1);
}

__global__ __launch_bounds__(256) void scan_blocksums(const int* __restrict__ deg, int* __restrict__ bsum, int n) {
  __shared__ int red[256];
  int t = threadIdx.x;
  int base = blockIdx.x * SCAN_CHUNK + t * 8;
  int s = 0;
#pragma unroll
  for (int j = 0; j < 8; ++j) {
    int i = base + j;
    if (i < n) s += deg[i];
  }
  red[t] = s;
  __syncthreads();
  for (int off = 128; off > 0; off >>= 1) {
    if (t < off) red[t] += red[t + off];
    __syncthreads();
  }
  if (t == 0) bsum[blockIdx.x] = red[0];
}

__global__ __launch_bounds__(256) void scan_offsets(const int* __restrict__ bsum, int* __restrict__ boff, int nb) {
  __shared__ int s[256];
  int t = threadIdx.x;
  int v = (t < nb) ? bsum[t] : 0;
  s[t] = v;
  __syncthreads();
  for (int off = 1; off < 256; off <<= 1) {
    int u = (t >= off) ? s[t - off] : 0;
    __syncthreads();
    s[t] += u;
    __syncthreads();
  }
  if (t < nb) boff[t] = (t == 0) ? 0 : s[t - 1];
}

__global__ __launch_bounds__(256) void scan_write(const int* __restrict__ deg, const int* __restrict__ boff,
                                                  int* __restrict__ rowptr, float* __restrict__ dinv, int n) {
  __shared__ int red[256];
  int t = threadIdx.x;
  int base = blockIdx.x * SCAN_CHUNK + t * 8;
  int v[8];
  int s = 0;
#pragma unroll
  for (int j = 0; j < 8; ++j) {
    int i = base + j;
    v[j] = (i < n) ? deg[i] : 0;
    s += v[j];
  }
  red[t] = s;
  __syncthreads();
  for (int off = 1; off < 256; off <<= 1) {
    int u = (t >= off) ? red[t - off] : 0;
    __syncthreads();
    red[t] += u;
    __syncthreads();
  }
  int run = red[t] - s + boff[blockIdx.x];
#pragma unroll
  for (int j = 0; j < 8; ++j) {
    int i = base + j;
    if (i < n) {
      rowptr[i] = run;
      dinv[i] = rsqrtf((float)v[j] + 1.0f);
    }
    run += v[j];
  }
}

__global__ __launch_bounds__(256) void fill_csr(const int* __restrict__ ei, const int* __restrict__ rowptr,
                                                int* __restrict__ cursor, int* __restrict__ col, int E) {
  int e = blockIdx.x * 256 + threadIdx.x;
  if (e < E) {
    int d = ei[E + e];
    int pos = atomicAdd(&cursor[d], 1);
    col[rowptr[d] + pos] = ei[e];
  }
}

// ---------------- weight repack into MFMA B-fragment order (bf16) ----------------
__global__ __launch_bounds__(256) void repack_w128(const float* __restrict__ W, short* __restrict__ wp) {
  int idx = blockIdx.x * 256 + threadIdx.x;  // 4*8*64*8 = 16384
  if (idx < 16384) {
    int j = idx & 7, lane = (idx >> 3) & 63, t = (idx >> 9) & 7, kc = idx >> 12;
    int k = kc * 32 + (lane >> 4) * 8 + j;
    int nn = t * 16 + (lane & 15);
    wp[idx] = f2bs(W[k * HDIM + nn]);
  }
}

__global__ __launch_bounds__(256) void repack_wcp(const float* __restrict__ Wfc, short* __restrict__ wp) {
  int idx = blockIdx.x * 256 + threadIdx.x;  // 4*2*64*8 = 4096
  if (idx < 4096) {
    int j = idx & 7, lane = (idx >> 3) & 63, t = (idx >> 9) & 1, kc = idx >> 10;
    int k = kc * 32 + (lane >> 4) * 8 + j;
    int nn = t * 16 + (lane & 15);
    float v = (nn < 16) ? Wfc[k * NC + nn] : Wfc[(HDIM + k) * NC + (nn - 16)];
    wp[idx] = f2bs(v);
  }
}

// ---------------- MFMA GEMM: Y[n x NCOL] = X[n x 128] @ W, K=128 ----------------
// SCALE: multiply output row r by dscale[r] before store (pre-scales messages by dinv).
template<int NCOL, bool FP32IN, bool FP32OUT, bool SCALE>
__global__ __launch_bounds__(256) void gemm_mfma(const void* __restrict__ Xv, const short* __restrict__ wpack,
                                                 void* __restrict__ Yv, const float* __restrict__ dscale, int n) {
  constexpr int NT = NCOL / 16;
  __shared__ short sw[4 * NT * 512];
  int tid = threadIdx.x;
  {
    const float4* wg = (const float4*)wpack;
    float4* sg = (float4*)sw;
    for (int i = tid; i < 4 * NT * 512 / 8; i += 256) sg[i] = wg[i];
  }
  __syncthreads();
  int wave = tid >> 6, lane = tid & 63;
  int quad = lane >> 4;
  int row = blockIdx.x * 64 + wave * 16 + (lane & 15);
  bool rowok = row < n;
  float4v acc[NT];
#pragma unroll
  for (int t = 0; t < NT; ++t) acc[t] = (float4v){0.f, 0.f, 0.f, 0.f};

#pragma unroll
  for (int kc = 0; kc < 4; ++kc) {
    short8 af = {0, 0, 0, 0, 0, 0, 0, 0};
    if (rowok) {
      if (FP32IN) {
        const float* xp = (const float*)Xv + (size_t)row * 128 + kc * 32 + quad * 8;
        float4 x0 = *(const float4*)xp;
        float4 x1 = *(const float4*)(xp + 4);
        af[0] = f2bs(x0.x); af[1] = f2bs(x0.y); af[2] = f2bs(x0.z); af[3] = f2bs(x0.w);
        af[4] = f2bs(x1.x); af[5] = f2bs(x1.y); af[6] = f2bs(x1.z); af[7] = f2bs(x1.w);
      } else {
        af = *(const short8*)((const short*)Xv + (size_t)row * 128 + kc * 32 + quad * 8);
      }
    }
#pragma unroll
    for (int t = 0; t < NT; ++t) {
      short8 bfr = *(const short8*)(sw + (kc * NT + t) * 512 + lane * 8);
      acc[t] = __builtin_amdgcn_mfma_f32_16x16x32_bf16(af, bfr, acc[t], 0, 0, 0);
    }
  }
  // C/D layout: col = lane&15, row = quad*4 + reg
  int orow0 = blockIdx.x * 64 + wave * 16 + quad * 4;
  float dv[4] = {1.f, 1.f, 1.f, 1.f};
  if constexpr (SCALE) {
#pragma unroll
    for (int r = 0; r < 4; ++r) dv[r] = (orow0 + r < n) ? dscale[orow0 + r] : 0.f;
  }
#pragma unroll
  for (int t = 0; t < NT; ++t) {
    int ocol = t * 16 + (lane & 15);
#pragma unroll
    for (int r = 0; r < 4; ++r) {
      int orow = orow0 + r;
      if (orow < n) {
        float val = acc[t][r];
        if constexpr (SCALE) val *= dv[r];
        if (FP32OUT)
          ((float*)Yv)[(size_t)orow * NCOL + ocol] = val;
        else
          ((__hip_bfloat16*)Yv)[(size_t)orow * NCOL + ocol] = (__hip_bfloat16)val;
      }
    }
  }
}

// ---------------- aggregation over pre-scaled rows hs = (h@W)*dinv ----------------
// 256 thr = 4 waves; each 16-lane quarter owns one node; lane covers 8 features (short8 = 16B).
// One wave gather instruction moves 4 rows x 256B = 1024B. col loads are software-pipelined.
__global__ __launch_bounds__(256) void agg_vec(const __hip_bfloat16* __restrict__ hs, const float* __restrict__ dinv,
                                               const int* __restrict__ rowptr, const int* __restrict__ deg,
                                               const int* __restrict__ col, const float* __restrict__ bias,
                                               __hip_bfloat16* __restrict__ hout, int N) {
  int tid = threadIdx.x;
  int wave = tid >> 6, lane = tid & 63;
  int q = lane >> 4, ft = lane & 15;
  int i = blockIdx.x * 16 + wave * 4 + q;
  bool ok = i < N;
  int iS = ok ? i : (N - 1);
  int s0 = rowptr[iS];
  int dg = ok ? deg[iS] : 0;
  float di = dinv[iS];
  const short* hb = (const short*)hs;
  // self term: hs[i] (already hpre[i]*dinv[i]); final *di below gives dinv^2.
  short8 selfv = *(const short8*)(hb + (size_t)iS * 128 + ft * 8);
  float acc[8];
#pragma unroll
  for (int j = 0; j < 8; ++j) acc[j] = bs2f(selfv[j]);
  // wave-level max degree over the 4 quarters (predicated loop tail)
  int mx = dg;
  mx = max(mx, __shfl_xor(mx, 16));
  mx = max(mx, __shfl_xor(mx, 32));
  // software pipeline: indices for iteration it fetched at it-2
  int cA = 0, cB = 0;
  if (0 < dg) cA = col[s0];
  if (1 < dg) cB = col[s0 + 1];
  for (int it = 0; it < mx; it += 2) {
    int nA = 0, nB = 0;
    if (it + 2 < dg) nA = col[s0 + it + 2];
    if (it + 3 < dg) nB = col[s0 + it + 3];
    if (it < dg) {
      short8 r0 = *(const short8*)(hb + (size_t)cA * 128 + ft * 8);
#pragma unroll
      for (int j = 0; j < 8; ++j) acc[j] += bs2f(r0[j]);
    }
    if (it + 1 < dg) {
      short8 r1 = *(const short8*)(hb + (size_t)cB * 128 + ft * 8);
#pragma unroll
      for (int j = 0; j < 8; ++j) acc[j] += bs2f(r1[j]);
    }
    cA = nA; cB = nB;
  }
  if (ok) {
    float4 b0 = *(const float4*)(bias + ft * 8);
    float4 b1 = *(const float4*)(bias + ft * 8 + 4);
    float bb[8] = {b0.x, b0.y, b0.z, b0.w, b1.x, b1.y, b1.z, b1.w};
    short8 o;
#pragma unroll
    for (int j = 0; j < 8; ++j) {
      float v = fmaxf(fmaf(acc[j], di, bb[j]), 0.f);
      o[j] = f2bs(v);
    }
    *(short8*)((short*)hout + (size_t)i * 128 + ft * 8) = o;
  }
}

// ---------------- edge head ----------------
__global__ __launch_bounds__(256) void edge_kernel(const int* __restrict__ ei, const float* __restrict__ ea,
                                                   const float* __restrict__ PQ, const float* __restrict__ Wfc,
                                                   const float* __restrict__ bfc, float* __restrict__ out, int E) {
  __shared__ float swe[D_E * NC];
  __shared__ float sb[NC];
  __shared__ float sea[256 * (D_E + 1)];
  int tid = threadIdx.x;
  int e0 = blockIdx.x * 256;
  for (int i = tid; i < D_E * NC; i += 256) {
    int j = i / NC, c = i % NC;
    swe[i] = Wfc[(2 * HDIM + j) * NC + c];
  }
  if (tid < NC) sb[tid] = bfc[tid];
  for (int i = tid; i < 256 * (D_E / 4); i += 256) {
    int le = i / (D_E / 4), f = i % (D_E / 4);
    int ge = e0 + le;
    float4 v = make_float4(0.f, 0.f, 0.f, 0.f);
    if (ge < E) v = *(const float4*)(ea + (size_t)ge * D_E + f * 4);
    float* p = sea + le * (D_E + 1) + f * 4;
    p[0] = v.x; p[1] = v.y; p[2] = v.z; p[3] = v.w;
  }
  __syncthreads();

  int e = e0 + tid;
  int s = 0, d = 0;
  if (e < E) { s = ei[e]; d = ei[E + e]; }
  float l[NC];
  {
    const float* p1 = PQ + (size_t)s * 32;
    const float* p2 = PQ + (size_t)d * 32 + 16;
#pragma unroll
    for (int c = 0; c < NC; ++c) l[c] = p1[c] + p2[c] + sb[c];
  }
  const float* myea = sea + tid * (D_E + 1);
#pragma unroll
  for (int j = 0; j < D_E; ++j) {
    float a = myea[j];
#pragma unroll
    for (int c = 0; c < NC; ++c) l[c] = fmaf(a, swe[j * NC + c], l[c]);
  }
  float m = l[0];
#pragma unroll
  for (int c = 1; c < NC; ++c) m = fmaxf(m, l[c]);
  float sum = 0.f;
#pragma unroll
  for (int c = 0; c < NC; ++c) sum += __expf(l[c] - m);
  float lse = __logf(sum) + m;
  if (e < E) {
    float4* po = (float4*)(out + (size_t)e * NC);
    po[0] = make_float4(l[0] - lse, l[1] - lse, l[2] - lse, l[3] - lse);
    po[1] = make_float4(l[4] - lse, l[5] - lse, l[6] - lse, l[7] - lse);
    po[2] = make_float4(l[8] - lse, l[9] - lse, l[10] - lse, l[11] - lse);
    po[3] = make_float4(l[12] - lse, l[13] - lse, l[14] - lse, l[15] - lse);
  }
}

// ---------------- launch ----------------

extern "C" void kernel_launch(void* const* d_in, const int* in_sizes, int n_in,
                              void* d_out, int out_size, void* d_ws, size_t ws_size,
                              hipStream_t stream) {
  const float* x   = (const float*)d_in[0];
  const int*   ei  = (const int*)d_in[1];
  const float* ea  = (const float*)d_in[2];
  const float* W1  = (const float*)d_in[3];
  const float* b1  = (const float*)d_in[4];
  const float* W2  = (const float*)d_in[5];
  const float* b2  = (const float*)d_in[6];
  const float* W3  = (const float*)d_in[7];
  const float* b3  = (const float*)d_in[8];
  const float* Wfc = (const float*)d_in[9];
  const float* bfc = (const float*)d_in[10];
  float* out = (float*)d_out;
  int N = in_sizes[0] / D_IN;
  int E = in_sizes[1] / 2;

  char* w = (char*)d_ws;
  size_t off = 0;
  auto alloc = [&](size_t bytes) -> char* {
    char* p = w + off;
    off += (bytes + 255) & ~(size_t)255;
    return p;
  };
  __hip_bfloat16* A = (__hip_bfloat16*)alloc((size_t)N * HDIM * 2);  // 25.6 MB
  __hip_bfloat16* B = (__hip_bfloat16*)alloc((size_t)N * HDIM * 2);  // 25.6 MB
  float* PQ     = (float*)alloc((size_t)N * 32 * 4);                 // 12.8 MB
  int*   col    = (int*)alloc((size_t)E * 4);
  int*   deg    = (int*)alloc((size_t)N * 4);
  int*   cursor = (int*)alloc((size_t)N * 4);
  float* dinv   = (float*)alloc((size_t)N * 4);
  int*   rowptr = (int*)alloc((size_t)N * 4);
  int*   bsum   = (int*)alloc(1024 * 4);
  int*   boff   = (int*)alloc(1024 * 4);
  short* wp1    = (short*)alloc(16384 * 2);
  short* wp2    = (short*)alloc(16384 * 2);
  short* wp3    = (short*)alloc(16384 * 2);
  short* wpc    = (short*)alloc(4096 * 2);

  hipMemsetAsync(deg, 0, (size_t)N * 4, stream);
  hipMemsetAsync(cursor, 0, (size_t)N * 4, stream);

  int eb = (E + 255) / 256;
  int sb = (N + SCAN_CHUNK - 1) / SCAN_CHUNK;
  count_deg<<<eb, 256, 0, stream>>>(ei, deg, E);
  scan_blocksums<<<sb, 256, 0, stream>>>(deg, bsum, N);
  scan_offsets<<<1, 256, 0, stream>>>(bsum, boff, sb);
  scan_write<<<sb, 256, 0, stream>>>(deg, boff, rowptr, dinv, N);
  fill_csr<<<eb, 256, 0, stream>>>(ei, rowptr, cursor, col, E);
  repack_w128<<<64, 256, 0, stream>>>(W1, wp1);
  repack_w128<<<64, 256, 0, stream>>>(W2, wp2);
  repack_w128<<<64, 256, 0, stream>>>(W3, wp3);
  repack_wcp<<<16, 256, 0, stream>>>(Wfc, wpc);

  int gb = (N + 63) / 64;
  int ab = (N + 15) / 16;
  gemm_mfma<128, true,  false, true ><<<gb, 256, 0, stream>>>(x, wp1, A, dinv, N);
  agg_vec<<<ab, 256, 0, stream>>>(A, dinv, rowptr, deg, col, b1, B, N);
  gemm_mfma<128, false, false, true ><<<gb, 256, 0, stream>>>(B, wp2, A, dinv, N);
  agg_vec<<<ab, 256, 0, stream>>>(A, dinv, rowptr, deg, col, b2, B, N);
  gemm_mfma<128, false, false, true ><<<gb, 256, 0, stream>>>(B, wp3, A, dinv, N);
  agg_vec<<<ab, 256, 0, stream>>>(A, dinv, rowptr, deg, col, b3, B, N);
  gemm_mfma<32,  false, true,  false><<<gb, 256, 0, stream>>>(B, wpc, PQ, nullptr, N);
  edge_kernel<<<eb, 256, 0, stream>>>(ei, ea, PQ, Wfc, bfc, out, E);
}